// Round 7
// baseline (272.608 us; speedup 1.0000x reference)
//
#include <hip/hip_runtime.h>
#include <hip/hip_cooperative_groups.h>

namespace cg = cooperative_groups;

#define B_SZ 1024
#define DIN 512
#define HH 512   // H
#define DOUT 512

typedef short bf16x8 __attribute__((ext_vector_type(8)));
typedef float f32x4 __attribute__((ext_vector_type(4)));

__device__ __forceinline__ unsigned short f2bf(float f) {
    unsigned int u = __float_as_uint(f);
    u += 0x7FFFu + ((u >> 16) & 1u);          // RTNE
    return (unsigned short)(u >> 16);
}
__device__ __forceinline__ float bf2f(unsigned short s) {
    return __uint_as_float(((unsigned int)s) << 16);
}

// pack 8 fp32 -> 8 bf16 (term==1 -> lo residual, else hi)
__device__ __forceinline__ uint4 cvt8(const float4& a0, const float4& a1, int term) {
    const float av[8] = {a0.x, a0.y, a0.z, a0.w, a1.x, a1.y, a1.z, a1.w};
    unsigned int p[4];
    #pragma unroll
    for (int q = 0; q < 4; ++q) {
        float f0 = av[2 * q], f1 = av[2 * q + 1];
        unsigned short h0 = f2bf(f0), h1 = f2bf(f1);
        if (term == 1) { h0 = f2bf(f0 - bf2f(h0)); h1 = f2bf(f1 - bf2f(h1)); }
        p[q] = (unsigned int)h0 | ((unsigned int)h1 << 16);
    }
    uint4 v; v.x = p[0]; v.y = p[1]; v.z = p[2]; v.w = p[3];
    return v;
}

// async global->LDS, 16B/lane. LDS dest is WAVE-UNIFORM base + lane*16 (m104);
// our staging layout is exactly linear in that order, so this applies directly.
__device__ __forceinline__ void gload_lds16(const void* g, void* l) {
    __builtin_amdgcn_global_load_lds(
        (__attribute__((address_space(1))) void*)g,
        (__attribute__((address_space(3))) void*)l, 16, 0, 0);
}

// ---------------------------------------------------------------------------
// bf16 hi/lo split GEMM scheme (K'=1536 = 3 terms x 512):
//   C = AhiWhi + AloWhi + AhiWlo  (~fp32 accurate)
// A terms over k': hi, lo, hi (converted on the fly in gemm staging).
// B terms: hi, hi, lo (prepped into Bfr[48 ks][32 nf][64 lanes]{uint4}).
// ---------------------------------------------------------------------------
__device__ __forceinline__ void convW_body(const float* __restrict__ W,
                                           uint4* __restrict__ dst, int t) {
    const int lane = t & 63;
    const int fb   = t >> 6;         // ks*32 + nf
    const int ks   = fb >> 5;
    const int nf   = fb & 31;
    const int col  = nf * 16 + (lane & 15);
    const int kb   = ks * 32 + ((lane >> 4) << 3);
    const int term = kb >> 9;        // 0,1,2 -> hi,hi,lo
    const int c0   = kb & 511;
    unsigned short o[8];
    #pragma unroll
    for (int j = 0; j < 8; ++j) {
        const float f = W[(size_t)(c0 + j) * 512 + col];
        unsigned short hi = f2bf(f);
        o[j] = (term == 2) ? f2bf(f - bf2f(hi)) : hi;
    }
    uint4 v;
    v.x = (unsigned int)o[0] | ((unsigned int)o[1] << 16);
    v.y = (unsigned int)o[2] | ((unsigned int)o[3] << 16);
    v.z = (unsigned int)o[4] | ((unsigned int)o[5] << 16);
    v.w = (unsigned int)o[6] | ((unsigned int)o[7] << 16);
    dst[t] = v;
}

// scan weight packs, consumption-ordered:
//  wdg[i*64+l]  = diag elem (row i, col 64*(i>>6)+l), masked (col>i), row-511 pad
//  wbk[CB + ((s*NK+k)*64+l)] = bulk elem (row 64C+s, col 64*(C+1+k)+l), no mask
template <int C>
__device__ __forceinline__ void pack_bulk(const float* __restrict__ W_hh,
                                          const float* __restrict__ b_hh,
                                          float2* __restrict__ wbk, int e) {
    constexpr int NK = 7 - C;
    constexpr int CB = (C==0?0:C==1?7:C==2?13:C==3?18:C==4?22:C==5?25:27) * 4096;
    const int s   = e / (NK * 64);           // compile-time NK -> magic mul
    const int rem = e - s * (NK * 64);
    const int row = 64 * C + s;
    const int col = 64 * (C + 1) + rem;
    float2 o;
    o.x = W_hh[(size_t)row * 512 + col];
    o.y = b_hh[(size_t)row * 512 + col];
    wbk[CB + e] = o;
}

// ---------------------------------------------------------------------------
// prep phase: grid-stride over 344064 tasks (131072 threads x ~2.6)
//   [0,32768)        wdg diag pack
//   [32768,147456)   wbk bulk pack (segments 28672,24576,20480,16384,12288,8192,4096)
//   [147456,245760)  W_in  -> Bin
//   [245760,344064)  W_out -> Bout
// ---------------------------------------------------------------------------
__device__ __forceinline__ void prep_phase(const float* __restrict__ W_hh,
                                           const float* __restrict__ b_hh,
                                           float2* __restrict__ wdg,
                                           float2* __restrict__ wbk,
                                           const float* __restrict__ W_in,
                                           uint4* __restrict__ Bin,
                                           const float* __restrict__ W_out,
                                           uint4* __restrict__ Bout,
                                           int bid, int tid) {
    for (int gt = bid * 512 + tid; gt < 344064; gt += 131072) {
        if (gt < 32768) {
            const int i = gt >> 6, l = gt & 63;
            float2 o;
            if (i < 511 && l > (i & 63)) {
                const int col = ((i >> 6) << 6) + l;
                o.x = W_hh[(size_t)i * 512 + col];
                o.y = b_hh[(size_t)i * 512 + col];
            } else { o.x = 0.0f; o.y = -1.0f; }
            wdg[gt] = o;
        } else if (gt < 147456) {
            const int e = gt - 32768;
            if      (e < 28672)  pack_bulk<0>(W_hh, b_hh, wbk, e);
            else if (e < 53248)  pack_bulk<1>(W_hh, b_hh, wbk, e - 28672);
            else if (e < 73728)  pack_bulk<2>(W_hh, b_hh, wbk, e - 53248);
            else if (e < 90112)  pack_bulk<3>(W_hh, b_hh, wbk, e - 73728);
            else if (e < 102400) pack_bulk<4>(W_hh, b_hh, wbk, e - 90112);
            else if (e < 110592) pack_bulk<5>(W_hh, b_hh, wbk, e - 102400);
            else                 pack_bulk<6>(W_hh, b_hh, wbk, e - 110592);
        } else if (gt < 245760) {
            convW_body(W_in, Bin, gt - 147456);
        } else {
            convW_body(W_out, Bout, gt - 245760);
        }
    }
}

// ---------------------------------------------------------------------------
// MFMA GEMM phase: 512 threads (8 waves), tile 64x32, 256 blocks (1/CU).
// Identical logic to r5's passing mfma_gemm, as a device function.
// ---------------------------------------------------------------------------
template <bool ACT>
__device__ __forceinline__ void gemm_body(const float* __restrict__ A,
                                          const uint4* __restrict__ Bg,
                                          const float* __restrict__ bias,
                                          float* __restrict__ Cc,
                                          uint4 (*lds)[768],
                                          int bx, int by, int tid) {
    const int lane = tid & 63;
    const int w    = tid >> 6;
    const int mfw  = w & 3;
    const int nfw  = w >> 2;
    const int mf0  = bx * 4;
    const int nf0  = by * 2;

    const int ks_s = tid >> 8;
    const int mf_s = (tid >> 6) & 3;
    const int arow = (mf0 + mf_s) * 16 + (lane & 15);
    const int koff = (lane >> 4) << 3;
    const int bks  = tid >> 7;
    const int bnf  = (tid >> 6) & 1;

    float4 Ra0, Ra1; uint4 R2;
    auto stage = [&](int s) {
        const int kp = (s * 2 + ks_s) * 32 + koff;
        const int c  = kp & 511;
        Ra0 = *(const float4*)&A[(size_t)arow * 512 + c];
        Ra1 = *(const float4*)&A[(size_t)arow * 512 + c + 4];
        if (tid < 256)
            R2 = Bg[(size_t)((s * 2 + bks) * 32 + nf0 + bnf) * 64 + lane];
    };
    auto write_tile = [&](int buf, int s) {
        const int kp = (s * 2 + ks_s) * 32 + koff;
        lds[buf][ks_s * 256 + mf_s * 64 + lane] = cvt8(Ra0, Ra1, kp >> 9);
        if (tid < 256)
            lds[buf][512 + bks * 128 + bnf * 64 + lane] = R2;
    };

    f32x4 acc = {0.f, 0.f, 0.f, 0.f};

    stage(0);
    write_tile(0, 0);
    stage(1);
    __syncthreads();

    for (int s = 0; s < 24; ++s) {
        const int cur = s & 1;
        if (s + 1 < 24) write_tile(cur ^ 1, s + 1);
        if (s + 2 < 24) stage(s + 2);
        __builtin_amdgcn_sched_barrier(0);

        bf16x8 aF0 = *(const bf16x8*)&lds[cur][          mfw * 64 + lane];
        bf16x8 aF1 = *(const bf16x8*)&lds[cur][256     + mfw * 64 + lane];
        bf16x8 bF0 = *(const bf16x8*)&lds[cur][512     + nfw * 64 + lane];
        bf16x8 bF1 = *(const bf16x8*)&lds[cur][512+128 + nfw * 64 + lane];
        acc = __builtin_amdgcn_mfma_f32_16x16x32_bf16(aF0, bF0, acc, 0, 0, 0);
        acc = __builtin_amdgcn_mfma_f32_16x16x32_bf16(aF1, bF1, acc, 0, 0, 0);
        __syncthreads();
    }

    const int colg  = (nf0 + nfw) * 16 + (lane & 15);
    const float bv  = bias[colg];
    const int rbase = (mf0 + mfw) * 16 + ((lane >> 4) << 2);
    #pragma unroll
    for (int r = 0; r < 4; ++r) {
        float v = acc[r] + bv;
        if (ACT) { v = fmaxf(v, 0.f); v = v * v; }
        Cc[(size_t)(rbase + r) * 512 + colg] = v;
    }
}

// ---------------------------------------------------------------------------
// Scan phase v7: diag register window + bulk via global_load_lds pipeline.
// 256 blocks x 8 waves; waves 0-3 each own one batch row (bid*4+wave), waves
// 4-7 only help stage + hit barriers. TS=16 steps/tile -> 4 tiles/chunk, tile
// = 512*NK float4 -> each of 512 threads issues exactly NK gload_lds16 ops
// (no relay VGPRs -> no spill, the v3/v5/v6 failure mode). Single 56KB LDS
// buffer: issue tile -> syncthreads (drains vmcnt) -> compute -> syncthreads.
// FP accumulation order per column unchanged -> same numerics as v2-v6.
// ---------------------------------------------------------------------------
template <int C>
__device__ __forceinline__ void scan_chunk(const float2* __restrict__ wdg,
                                           const float2* __restrict__ wbk,
                                           float2* __restrict__ smb,
                                           float hr[8], int lane, int wave, int tid) {
    constexpr int NK = 7 - C;
    constexpr int CB = (C==0?0:C==1?7:C==2?13:C==3?18:C==4?22:C==5?25:C==6?27:28) * 4096;
    const float2* dptr = wdg + (64 * C) * 64 + lane;
    const char* gchunk = (const char*)(wbk + CB);

    // diag window preload (waves 0-3; 32 VGPRs, proven resident in v5)
    float2 Wd[16];
    if (wave < 4) {
        #pragma unroll
        for (int q = 0; q < 16; ++q) Wd[q] = dptr[q * 64];
    }
    // stage tile 0 (all 8 waves, no registers consumed)
    if constexpr (NK > 0) {
        #pragma unroll
        for (int u = 0; u < NK; ++u)
            gload_lds16(gchunk + (size_t)(u * 512 + tid) * 16,
                        (char*)smb + (size_t)(u * 512 + wave * 64) * 16);
    }

    // serial diagonal: 64 steps, rotating register window (covers tile-0 flight)
    if (wave < 4) {
        for (int t = 0; t < 4; ++t) {
            #pragma unroll
            for (int q = 0; q < 16; ++q) {
                const int s = t * 16 + q;
                if (!(C == 7 && s == 63)) {    // no global step 511
                    const float hi = __uint_as_float(
                        __builtin_amdgcn_readlane(__float_as_uint(hr[C]), s));
                    const float tv = fmaf(hi, Wd[q].x, Wd[q].y);
                    const float rv = fmaxf(tv, 0.f);
                    hr[C] = fmaf(rv, rv, hr[C]);
                }
                if (t < 3) Wd[q] = dptr[(s + 16) * 64];
            }
        }
    }

    // streaming bulk: hr[C] final -> all 64 readlanes independent
    if constexpr (NK > 0) {
        __syncthreads();                       // tile 0 resident (vmcnt drained)
        for (int t = 0; t < 4; ++t) {
            if (wave < 4) {
                #pragma unroll 2
                for (int s = 0; s < 16; ++s) {
                    const float hi = __uint_as_float(
                        __builtin_amdgcn_readlane(__float_as_uint(hr[C]), t * 16 + s));
                    #pragma unroll
                    for (int k = 0; k < NK; ++k) {
                        const float2 wv = smb[(s * NK + k) * 64 + lane];
                        const float tv = fmaf(hi, wv.x, wv.y);
                        const float rv = fmaxf(tv, 0.f);
                        hr[C + 1 + k] = fmaf(rv, rv, hr[C + 1 + k]);
                    }
                }
            }
            __syncthreads();                   // all reads of this tile done
            if (t < 3) {
                #pragma unroll
                for (int u = 0; u < NK; ++u)
                    gload_lds16(gchunk + (size_t)((t + 1) * NK * 512 + u * 512 + tid) * 16,
                                (char*)smb + (size_t)(u * 512 + wave * 64) * 16);
                __syncthreads();               // tile t+1 resident
            }
        }
    }
}

__device__ __forceinline__ void scan_phase(const float2* __restrict__ wdg,
                                           const float2* __restrict__ wbk,
                                           float* __restrict__ h,
                                           float2* __restrict__ smb,
                                           int bid, int tid) {
    const int lane = tid & 63;
    const int wave = tid >> 6;
    float hr[8] = {0.f, 0.f, 0.f, 0.f, 0.f, 0.f, 0.f, 0.f};
    float* hrow = h;
    if (wave < 4) {
        hrow = h + (size_t)(bid * 4 + wave) * HH;
        #pragma unroll
        for (int k = 0; k < 8; ++k) hr[k] = hrow[lane + 64 * k];
    }
    scan_chunk<0>(wdg, wbk, smb, hr, lane, wave, tid);
    scan_chunk<1>(wdg, wbk, smb, hr, lane, wave, tid);
    scan_chunk<2>(wdg, wbk, smb, hr, lane, wave, tid);
    scan_chunk<3>(wdg, wbk, smb, hr, lane, wave, tid);
    scan_chunk<4>(wdg, wbk, smb, hr, lane, wave, tid);
    scan_chunk<5>(wdg, wbk, smb, hr, lane, wave, tid);
    scan_chunk<6>(wdg, wbk, smb, hr, lane, wave, tid);
    scan_chunk<7>(wdg, wbk, smb, hr, lane, wave, tid);
    if (wave < 4) {
        #pragma unroll
        for (int k = 0; k < 8; ++k) hrow[lane + 64 * k] = hr[k];
    }
}

// ---------------------------------------------------------------------------
// Fused cooperative kernel: prep -> gemm1 -> scan -> gemm2, grid.sync between.
// 256 blocks x 512 threads = 1 block/CU (coop co-residency guaranteed by
// launch_bounds(512,2): VGPR<=256, LDS 57KB static).
// ---------------------------------------------------------------------------
__global__ __launch_bounds__(512, 2)
void fused(const float* x, const float* W_in, const float* b_in,
           const float* W_hh, const float* b_hh,
           const float* W_out, const float* b_out,
           float2* wdg, float2* wbk, float* h,
           uint4* Bin, uint4* Bout, float* out) {
    __shared__ __align__(16) float2 smem[7168];    // 56KB, reused per phase
    const int tid = threadIdx.x;
    const int bid = blockIdx.x;
    cg::grid_group grid = cg::this_grid();

    prep_phase(W_hh, b_hh, wdg, wbk, W_in, Bin, W_out, Bout, bid, tid);
    grid.sync();
    gemm_body<true>(x, Bin, b_in, h, (uint4(*)[768])smem, bid & 15, bid >> 4, tid);
    grid.sync();
    scan_phase(wdg, wbk, h, smem, bid, tid);
    grid.sync();
    gemm_body<false>(h, Bout, b_out, out, (uint4(*)[768])smem, bid & 15, bid >> 4, tid);
}

// Fallback path (if cooperative launch is rejected): same device functions,
// 4 plain dispatches.
__global__ __launch_bounds__(512)
void prep_k(const float* W_hh, const float* b_hh, float2* wdg, float2* wbk,
            const float* W_in, uint4* Bin, const float* W_out, uint4* Bout) {
    prep_phase(W_hh, b_hh, wdg, wbk, W_in, Bin, W_out, Bout, blockIdx.x, threadIdx.x);
}
template <bool ACT>
__global__ __launch_bounds__(512, 2)
void gemm_k(const float* A, const uint4* Bg, const float* bias, float* Cc) {
    __shared__ uint4 lds[2][768];
    gemm_body<ACT>(A, Bg, bias, Cc, lds, blockIdx.x & 15, blockIdx.x >> 4, threadIdx.x);
}
__global__ __launch_bounds__(512, 2)
void scan_k(const float2* wdg, const float2* wbk, float* h) {
    __shared__ __align__(16) float2 smem[7168];
    scan_phase(wdg, wbk, h, smem, blockIdx.x, threadIdx.x);
}

// ---------------------------------------------------------------------------
// workspace layout (6.2 MB):
//   [0x000000, 0x040000) wdg  (512*64 f2 = 256 KB)
//   [0x040000, 0x120000) wbk  (114688 f2 = 896 KB)
//   [0x120000, 0x320000) h    (1024*512 fp32 = 2 MB)
//   [0x320000, 0x4A0000) Bin  (48*32*64 uint4 = 1.5 MB)
//   [0x4A0000, 0x620000) Bout (1.5 MB)
// ---------------------------------------------------------------------------
extern "C" void kernel_launch(void* const* d_in, const int* in_sizes, int n_in,
                              void* d_out, int out_size, void* d_ws, size_t ws_size,
                              hipStream_t stream) {
    const float* x     = (const float*)d_in[0];
    const float* W_in  = (const float*)d_in[1];
    const float* b_in  = (const float*)d_in[2];
    const float* W_hh  = (const float*)d_in[3];
    const float* b_hh  = (const float*)d_in[4];
    const float* W_out = (const float*)d_in[5];
    const float* b_out = (const float*)d_in[6];
    float* out = (float*)d_out;

    char* ws = (char*)d_ws;
    float2* wdg  = (float2*)ws;
    float2* wbk  = (float2*)(ws + 0x040000u);
    float*  h    = (float*)(ws + 0x120000u);
    uint4*  Bin  = (uint4*)(ws + 0x320000u);
    uint4*  Bout = (uint4*)(ws + 0x4A0000u);

    void* args[] = {(void*)&x, (void*)&W_in, (void*)&b_in, (void*)&W_hh,
                    (void*)&b_hh, (void*)&W_out, (void*)&b_out,
                    (void*)&wdg, (void*)&wbk, (void*)&h,
                    (void*)&Bin, (void*)&Bout, (void*)&out};
    hipError_t e = hipLaunchCooperativeKernel((const void*)fused, dim3(256),
                                              dim3(512), args, 0, stream);
    if (e != hipSuccess) {
        (void)hipGetLastError();               // clear sticky error
        prep_k<<<dim3(256), dim3(512), 0, stream>>>(W_hh, b_hh, wdg, wbk,
                                                    W_in, Bin, W_out, Bout);
        gemm_k<true><<<dim3(256), dim3(512), 0, stream>>>(x, Bin, b_in, h);
        scan_k<<<dim3(256), dim3(512), 0, stream>>>(wdg, wbk, h);
        gemm_k<false><<<dim3(256), dim3(512), 0, stream>>>(h, Bout, b_out, out);
    }
}

// Round 8
// 157.133 us; speedup vs baseline: 1.7349x; 1.7349x over previous
//
#include <hip/hip_runtime.h>

#define B_SZ 1024
#define DIN 512
#define HH 512   // H
#define DOUT 512

typedef short bf16x8 __attribute__((ext_vector_type(8)));
typedef float f32x4 __attribute__((ext_vector_type(4)));

__device__ __forceinline__ unsigned short f2bf(float f) {
    unsigned int u = __float_as_uint(f);
    u += 0x7FFFu + ((u >> 16) & 1u);          // RTNE
    return (unsigned short)(u >> 16);
}
__device__ __forceinline__ float bf2f(unsigned short s) {
    return __uint_as_float(((unsigned int)s) << 16);
}

// pack 8 fp32 -> 8 bf16 (term==1 -> lo residual, else hi)
__device__ __forceinline__ uint4 cvt8(const float4& a0, const float4& a1, int term) {
    const float av[8] = {a0.x, a0.y, a0.z, a0.w, a1.x, a1.y, a1.z, a1.w};
    unsigned int p[4];
    #pragma unroll
    for (int q = 0; q < 4; ++q) {
        float f0 = av[2 * q], f1 = av[2 * q + 1];
        unsigned short h0 = f2bf(f0), h1 = f2bf(f1);
        if (term == 1) { h0 = f2bf(f0 - bf2f(h0)); h1 = f2bf(f1 - bf2f(h1)); }
        p[q] = (unsigned int)h0 | ((unsigned int)h1 << 16);
    }
    uint4 v; v.x = p[0]; v.y = p[1]; v.z = p[2]; v.w = p[3];
    return v;
}

// async global->LDS, 16B/lane. LDS dest = WAVE-UNIFORM base + lane*16 (m104);
// global src is per-lane (m173). Proven correct in r7's fused run.
__device__ __forceinline__ void gload_lds16(const void* g, void* l) {
    __builtin_amdgcn_global_load_lds(
        (__attribute__((address_space(1))) void*)g,
        (__attribute__((address_space(3))) void*)l, 16, 0, 0);
}

// ---------------------------------------------------------------------------
// bf16 hi/lo split GEMM scheme (K'=1536 = 3 terms x 512):
//   C = AhiWhi + AloWhi + AhiWlo  (~fp32 accurate)
// A terms over k': hi, lo, hi (converted on the fly in gemm staging).
// B terms: hi, hi, lo (prepped into Bfr[48 ks][32 nf][64 lanes]{uint4}).
// ---------------------------------------------------------------------------
__device__ __forceinline__ void convW_body(const float* __restrict__ W,
                                           uint4* __restrict__ dst, int t) {
    const int lane = t & 63;
    const int fb   = t >> 6;         // ks*32 + nf
    const int ks   = fb >> 5;
    const int nf   = fb & 31;
    const int col  = nf * 16 + (lane & 15);
    const int kb   = ks * 32 + ((lane >> 4) << 3);
    const int term = kb >> 9;        // 0,1,2 -> hi,hi,lo
    const int c0   = kb & 511;
    unsigned short o[8];
    #pragma unroll
    for (int j = 0; j < 8; ++j) {
        const float f = W[(size_t)(c0 + j) * 512 + col];
        unsigned short hi = f2bf(f);
        o[j] = (term == 2) ? f2bf(f - bf2f(hi)) : hi;
    }
    uint4 v;
    v.x = (unsigned int)o[0] | ((unsigned int)o[1] << 16);
    v.y = (unsigned int)o[2] | ((unsigned int)o[3] << 16);
    v.z = (unsigned int)o[4] | ((unsigned int)o[5] << 16);
    v.w = (unsigned int)o[6] | ((unsigned int)o[7] << 16);
    dst[t] = v;
}

// scan weight packs, consumption-ordered:
//  wdg[i*64+l] = diag elem (row i, col 64*(i>>6)+l), masked (col>i), row-511 pad
//  wbk[CB + ((s*NK+k)*64+l)] = bulk elem (row 64C+s, col 64*(C+1+k)+l), no mask
template <int C>
__device__ __forceinline__ void pack_bulk(const float* __restrict__ W_hh,
                                          const float* __restrict__ b_hh,
                                          float2* __restrict__ wbk, int e) {
    constexpr int NK = 7 - C;
    constexpr int CB = (C==0?0:C==1?7:C==2?13:C==3?18:C==4?22:C==5?25:27) * 4096;
    const int s   = e / (NK * 64);           // compile-time NK -> magic mul
    const int rem = e - s * (NK * 64);
    const int row = 64 * C + s;
    const int col = 64 * (C + 1) + rem;
    float2 o;
    o.x = W_hh[(size_t)row * 512 + col];
    o.y = b_hh[(size_t)row * 512 + col];
    wbk[CB + e] = o;
}

// ---------------------------------------------------------------------------
// prep_all (block-range dispatch), 1344 blocks — unchanged from r5 (passing).
// ---------------------------------------------------------------------------
__global__ __launch_bounds__(256)
void prep_all(const float* __restrict__ W_hh, const float* __restrict__ b_hh,
              float2* __restrict__ wdg, float2* __restrict__ wbk,
              const float* __restrict__ W_in, uint4* __restrict__ Bin,
              const float* __restrict__ W_out, uint4* __restrict__ Bout) {
    const int b = blockIdx.x;
    const int tid = threadIdx.x;
    if (b < 128) {
        const int idx = b * 256 + tid;       // over 512*64
        const int i = idx >> 6, l = idx & 63;
        float2 o;
        if (i < 511 && l > (i & 63)) {
            const int col = ((i >> 6) << 6) + l;
            o.x = W_hh[(size_t)i * 512 + col];
            o.y = b_hh[(size_t)i * 512 + col];
        } else { o.x = 0.0f; o.y = -1.0f; }
        wdg[idx] = o;
    } else if (b < 576) {
        const int rb = b - 128;
        if      (rb < 112) pack_bulk<0>(W_hh, b_hh, wbk, (rb      ) * 256 + tid);
        else if (rb < 208) pack_bulk<1>(W_hh, b_hh, wbk, (rb - 112) * 256 + tid);
        else if (rb < 288) pack_bulk<2>(W_hh, b_hh, wbk, (rb - 208) * 256 + tid);
        else if (rb < 352) pack_bulk<3>(W_hh, b_hh, wbk, (rb - 288) * 256 + tid);
        else if (rb < 400) pack_bulk<4>(W_hh, b_hh, wbk, (rb - 352) * 256 + tid);
        else if (rb < 432) pack_bulk<5>(W_hh, b_hh, wbk, (rb - 400) * 256 + tid);
        else               pack_bulk<6>(W_hh, b_hh, wbk, (rb - 432) * 256 + tid);
    } else if (b < 960) {
        convW_body(W_in, Bin, (b - 576) * 256 + tid);
    } else {
        convW_body(W_out, Bout, (b - 960) * 256 + tid);
    }
}

// ---------------------------------------------------------------------------
// MFMA GEMM: 512 threads (8 waves = 2/SIMD). Unchanged from r5 (passing).
// ---------------------------------------------------------------------------
template <bool ACT>
__global__ __launch_bounds__(512, 2)
void mfma_gemm(const float* __restrict__ A,    // [1024][512] fp32
               const uint4* __restrict__ Bg,   // [48][32][64] uint4
               const float* __restrict__ bias,
               float* __restrict__ C) {
    __shared__ uint4 lds[2][768];
    const int tid  = threadIdx.x;
    const int lane = tid & 63;
    const int w    = tid >> 6;
    const int mfw  = w & 3;
    const int nfw  = w >> 2;
    const int mf0  = blockIdx.x * 4;
    const int nf0  = blockIdx.y * 2;

    const int ks_s = tid >> 8;
    const int mf_s = (tid >> 6) & 3;
    const int arow = (mf0 + mf_s) * 16 + (lane & 15);
    const int koff = (lane >> 4) << 3;
    const int bks  = tid >> 7;
    const int bnf  = (tid >> 6) & 1;

    float4 Ra0, Ra1; uint4 R2;
    auto stage = [&](int s) {
        const int kp = (s * 2 + ks_s) * 32 + koff;
        const int c  = kp & 511;
        Ra0 = *(const float4*)&A[(size_t)arow * 512 + c];
        Ra1 = *(const float4*)&A[(size_t)arow * 512 + c + 4];
        if (tid < 256)
            R2 = Bg[(size_t)((s * 2 + bks) * 32 + nf0 + bnf) * 64 + lane];
    };
    auto write_tile = [&](int buf, int s) {
        const int kp = (s * 2 + ks_s) * 32 + koff;
        lds[buf][ks_s * 256 + mf_s * 64 + lane] = cvt8(Ra0, Ra1, kp >> 9);
        if (tid < 256)
            lds[buf][512 + bks * 128 + bnf * 64 + lane] = R2;
    };

    f32x4 acc = {0.f, 0.f, 0.f, 0.f};

    stage(0);
    write_tile(0, 0);
    stage(1);
    __syncthreads();

    for (int s = 0; s < 24; ++s) {
        const int cur = s & 1;
        if (s + 1 < 24) write_tile(cur ^ 1, s + 1);
        if (s + 2 < 24) stage(s + 2);
        __builtin_amdgcn_sched_barrier(0);

        bf16x8 aF0 = *(const bf16x8*)&lds[cur][          mfw * 64 + lane];
        bf16x8 aF1 = *(const bf16x8*)&lds[cur][256     + mfw * 64 + lane];
        bf16x8 bF0 = *(const bf16x8*)&lds[cur][512     + nfw * 64 + lane];
        bf16x8 bF1 = *(const bf16x8*)&lds[cur][512+128 + nfw * 64 + lane];
        acc = __builtin_amdgcn_mfma_f32_16x16x32_bf16(aF0, bF0, acc, 0, 0, 0);
        acc = __builtin_amdgcn_mfma_f32_16x16x32_bf16(aF1, bF1, acc, 0, 0, 0);
        __syncthreads();
    }

    const int colg  = (nf0 + nfw) * 16 + (lane & 15);
    const float bv  = bias[colg];
    const int rbase = (mf0 + mfw) * 16 + ((lane >> 4) << 2);
    #pragma unroll
    for (int r = 0; r < 4; ++r) {
        float v = acc[r] + bv;
        if (ACT) { v = fmaxf(v, 0.f); v = v * v; }
        C[(size_t)(rbase + r) * 512 + colg] = v;
    }
}

// ---------------------------------------------------------------------------
// Sequential triangular scan, v8 (STANDALONE): diag register chain + bulk via
// global_load_lds double-buffer. 256 blocks x 4 waves; wave = one batch row;
// lane l owns cols l+64k.
//
// Per 64-step chunk C:
//  - diag: v5's proven DD=16 rotating register window (resident at VGPR 84,
//    launch_bounds(256,1)); 64-step serial chain from registers.
//  - bulk: TS=8 steps/tile -> 8 tiles of NK*4KB. Each tile staged by
//    global_load_lds (NK loads/thread, ZERO relay VGPRs -> nothing to spill,
//    the v3/v5/v6/v7 failure mode). 2x28KB LDS buffers; T3 minimum-2-phase:
//    issue tile t+1 -> compute tile t (ds_read_b64, 8B lane stride = free
//    2-way alias) -> __syncthreads (auto-drains vmcnt). Tile-0 flight hides
//    under the diag chain; tile t+1 flight hides under compute(t).
// FP accumulation order per column unchanged -> same numerics as v2-v7.
// ---------------------------------------------------------------------------
template <int C>
__device__ __forceinline__ void scan_chunk(const float2* __restrict__ wdg,
                                           const float2* __restrict__ wbk,
                                           float2 (* __restrict__ smb)[3584],
                                           float hr[8], int lane, int tid) {
    constexpr int NK = 7 - C;
    constexpr int CB = (C==0?0:C==1?7:C==2?13:C==3?18:C==4?22:C==5?25:C==6?27:27) * 4096;
    const float2* dptr = wdg + (64 * C) * 64 + lane;

    // diag window preload (32 VGPRs; proven resident in v5)
    float2 Wd[16];
    #pragma unroll
    for (int q = 0; q < 16; ++q) Wd[q] = dptr[q * 64];

    const char* gch = (const char*)(wbk + CB);
    char* lbase = (char*)(&smb[0][0]) + ((tid >> 6) << 10);   // + wave*1024
    auto stage = [&](int t, int buf) {
        const char* g = gch + (size_t)t * (NK * 4096);
        char* l = lbase + buf * 28672;
        #pragma unroll
        for (int u = 0; u < NK; ++u)     // dest wave-uniform; HW adds lane*16
            gload_lds16(g + (size_t)((u << 8) + tid) * 16, l + (u << 12));
    };
    if constexpr (NK > 0) stage(0, 0);   // tile-0 flight hides under diag

    // serial diagonal: 64 steps, rotating register window
    for (int t = 0; t < 4; ++t) {
        #pragma unroll
        for (int q = 0; q < 16; ++q) {
            const int s = t * 16 + q;
            if (!(C == 7 && s == 63)) {  // no global step 511
                const float hi = __uint_as_float(
                    __builtin_amdgcn_readlane(__float_as_uint(hr[C]), s));
                const float tv = fmaf(hi, Wd[q].x, Wd[q].y);
                const float rv = fmaxf(tv, 0.f);
                hr[C] = fmaf(rv, rv, hr[C]);
            }
            if (t < 3) Wd[q] = dptr[(s + 16) * 64];
        }
    }

    // streaming bulk: hr[C] final -> all 64 readlanes independent
    if constexpr (NK > 0) {
        __syncthreads();                 // drains vmcnt: tile 0 resident
        for (int t = 0; t < 8; ++t) {
            const int buf = t & 1;
            if (t + 1 < 8) stage(t + 1, buf ^ 1);
            __builtin_amdgcn_sched_barrier(0);   // pin issue above compute

            #pragma unroll 2
            for (int s = 0; s < 8; ++s) {
                const float hi = __uint_as_float(
                    __builtin_amdgcn_readlane(__float_as_uint(hr[C]), t * 8 + s));
                #pragma unroll
                for (int k = 0; k < NK; ++k) {
                    const float2 wv = smb[buf][(s * NK + k) * 64 + lane];
                    const float tv = fmaf(hi, wv.x, wv.y);
                    const float rv = fmaxf(tv, 0.f);
                    hr[C + 1 + k] = fmaf(rv, rv, hr[C + 1 + k]);
                }
            }
            __syncthreads();             // reads done; tile t+1 resident
        }
    }
}

__global__ __launch_bounds__(256, 1)
void scan_kernel(const float2* __restrict__ wdg, const float2* __restrict__ wbk,
                 float* __restrict__ h) {
    __shared__ __align__(16) float2 smb[2][3584];   // 2 x 28KB bulk buffers
    const int tid  = threadIdx.x;
    const int lane = tid & 63;
    const int wave = tid >> 6;
    const int row  = blockIdx.x * 4 + wave;         // 256 blocks x 4 waves
    float* hrow = h + (size_t)row * HH;

    float hr[8];
    #pragma unroll
    for (int k = 0; k < 8; ++k) hr[k] = hrow[lane + 64 * k];

    scan_chunk<0>(wdg, wbk, smb, hr, lane, tid);
    scan_chunk<1>(wdg, wbk, smb, hr, lane, tid);
    scan_chunk<2>(wdg, wbk, smb, hr, lane, tid);
    scan_chunk<3>(wdg, wbk, smb, hr, lane, tid);
    scan_chunk<4>(wdg, wbk, smb, hr, lane, tid);
    scan_chunk<5>(wdg, wbk, smb, hr, lane, tid);
    scan_chunk<6>(wdg, wbk, smb, hr, lane, tid);
    scan_chunk<7>(wdg, wbk, smb, hr, lane, tid);

    #pragma unroll
    for (int k = 0; k < 8; ++k) hrow[lane + 64 * k] = hr[k];
}

// ---------------------------------------------------------------------------
// workspace layout (6.2 MB):
//   [0x000000, 0x040000) wdg  (512*64 f2 = 256 KB)
//   [0x040000, 0x120000) wbk  (114688 f2 = 896 KB)
//   [0x120000, 0x320000) h    (1024*512 fp32 = 2 MB)
//   [0x320000, 0x4A0000) Bin  (48*32*64 uint4 = 1.5 MB)
//   [0x4A0000, 0x620000) Bout (1.5 MB)
// ---------------------------------------------------------------------------
extern "C" void kernel_launch(void* const* d_in, const int* in_sizes, int n_in,
                              void* d_out, int out_size, void* d_ws, size_t ws_size,
                              hipStream_t stream) {
    const float* x     = (const float*)d_in[0];
    const float* W_in  = (const float*)d_in[1];
    const float* b_in  = (const float*)d_in[2];
    const float* W_hh  = (const float*)d_in[3];
    const float* b_hh  = (const float*)d_in[4];
    const float* W_out = (const float*)d_in[5];
    const float* b_out = (const float*)d_in[6];
    float* out = (float*)d_out;

    char* ws = (char*)d_ws;
    float2* wdg  = (float2*)ws;
    float2* wbk  = (float2*)(ws + 0x040000u);
    float*  h    = (float*)(ws + 0x120000u);
    uint4*  Bin  = (uint4*)(ws + 0x320000u);
    uint4*  Bout = (uint4*)(ws + 0x4A0000u);

    // 1) prep: scan-weight packs + W_in/W_out bf16 hi/lo frag-linear split
    prep_all<<<dim3(1344), dim3(256), 0, stream>>>(W_hh, b_hh, wdg, wbk,
                                                   W_in, Bin, W_out, Bout);

    // 2) h0 = relu^2(x @ W_in + b_in)  (A-side split fused into staging)
    mfma_gemm<true><<<dim3(16, 16), dim3(512), 0, stream>>>(x, Bin, b_in, h);

    // 3) sequential triangular scan, in-place on h
    scan_kernel<<<dim3(256), dim3(256), 0, stream>>>(wdg, wbk, h);

    // 4) out = h @ W_out + b_out  (A-side split fused into staging)
    mfma_gemm<false><<<dim3(16, 16), dim3(512), 0, stream>>>(h, Bout, b_out, out);
}